// Round 11
// baseline (349.183 us; speedup 1.0000x reference)
//
#include <hip/hip_runtime.h>

#define NROWS 4096
#define DDIM  128
#define NHEAD 8
#define LOG2E 1.44269504088896f

// native 2^x  ->  single v_exp_f32 (ocml symbol always present in device libs)
extern "C" __device__ float __ocml_native_exp2_f32(float);

typedef __attribute__((ext_vector_type(8))) short    short8;
typedef __attribute__((ext_vector_type(8))) _Float16 half8;
typedef __attribute__((ext_vector_type(4))) float    floatx4;

__device__ __forceinline__ float bf2f(unsigned short u){
  unsigned v = ((unsigned)u) << 16;
  return __builtin_bit_cast(float, v);
}
__device__ __forceinline__ unsigned short f2bf(float f){
  unsigned u = __builtin_bit_cast(unsigned, f);
  u += 0x7FFFu + ((u >> 16) & 1u);
  return (unsigned short)(u >> 16);
}
__device__ __forceinline__ void split2(float v, unsigned short& hi, unsigned short& lo){
  hi = f2bf(v);
  lo = f2bf(v - bf2f(hi));
}
// async global->LDS, 16B per lane: LDS dest = wave-uniform base + lane*16.
__device__ __forceinline__ void async_cp16(const void* g, void* l){
  __builtin_amdgcn_global_load_lds(
      (const __attribute__((address_space(1))) void*)g,
      (__attribute__((address_space(3))) void*)l, 16, 0, 0);
}
// 16-lane (DPP row) max reduce via row_ror 8/4/2/1 — pure VALU, no lgkm.
__device__ __forceinline__ float dpp_max16(float v){
  int t;
  t = __builtin_amdgcn_update_dpp(0, __builtin_bit_cast(int, v), 0x128, 0xF, 0xF, false);
  v = fmaxf(v, __builtin_bit_cast(float, t));
  t = __builtin_amdgcn_update_dpp(0, __builtin_bit_cast(int, v), 0x124, 0xF, 0xF, false);
  v = fmaxf(v, __builtin_bit_cast(float, t));
  t = __builtin_amdgcn_update_dpp(0, __builtin_bit_cast(int, v), 0x122, 0xF, 0xF, false);
  v = fmaxf(v, __builtin_bit_cast(float, t));
  t = __builtin_amdgcn_update_dpp(0, __builtin_bit_cast(int, v), 0x121, 0xF, 0xF, false);
  v = fmaxf(v, __builtin_bit_cast(float, t));
  return v;
}

// fp32 sentinels: 500=ws too small, 1000=in_sizes mismatch, 2000=launch fail.
__global__ void fill_kernel(float* __restrict__ out, float val, int n){
  int i = blockIdx.x * 256 + threadIdx.x;
  if (i < n) out[i] = val;
}

// ---------------------------------------------------------------------------
// Kernel 0: prep — one-time bf16 hi/lo splits so proj/mlp do ZERO split2 VALU.
// W_k/v/q tiles: LDS-LINEAR chunk order with XOR swizzle baked in (proj).
// Wg: exact MFMA B-FRAGMENT order (mlp reads frags directly from global).
// x split to xh/xl row-major bf16 (direct short8 A-frag loads).
// ---------------------------------------------------------------------------
__global__ __launch_bounds__(256) void prep_kernel(
    const float* __restrict__ Wk, const float* __restrict__ Wv,
    const float* __restrict__ Wq, const float* __restrict__ Wg,
    const float* __restrict__ x,
    unsigned short* __restrict__ wpre, unsigned short* __restrict__ wgfrag,
    unsigned short* __restrict__ xh, unsigned short* __restrict__ xl)
{
  const int id = blockIdx.x * 256 + threadIdx.x;
  if (id < 49152) {              // W_k/v/q: 3 z * 8 h * 2 fh * 1024 chunks
    const int z = id >> 14, rem = id & 16383;
    const int h = rem >> 11, rem2 = rem & 2047;
    const int fh = rem2 >> 10, L = rem2 & 1023;
    const int d = L >> 3, m = L & 7;
    const int kk0 = (m ^ (d & 7)) << 3;
    const float* W = (z == 0 ? Wk : (z == 1 ? Wv : Wq)) + h * DDIM * DDIM;
    short8 hi8, lo8;
#pragma unroll
    for (int j = 0; j < 8; j++) {
      unsigned short hi, lo;
      split2(W[(fh * 64 + kk0 + j) * DDIM + d], hi, lo);
      hi8[j] = (short)hi; lo8[j] = (short)lo;
    }
    unsigned short* base = wpre + (size_t)((z * 8 + h) * 2 + fh) * 16384;
    *(short8*)(base + L * 8) = hi8;
    *(short8*)(base + 8192 + L * 8) = lo8;
  } else if (id < 51200) {       // Wg: 2048 ids = (fh, t2, c, lane), frag order
    const int t = id - 49152;
    const int fh = t >> 10, rem = t & 1023;
    const int t2 = rem >> 9, rem2 = rem & 511;
    const int c = rem2 >> 6, ln = rem2 & 63;
    const int quad = ln >> 4, l4 = ln & 15;
    const int col = c * 16 + l4;
    const int k0 = fh * 64 + t2 * 32 + quad * 8;
    short8 hi8, lo8;
#pragma unroll
    for (int j = 0; j < 8; j++) {
      unsigned short hi, lo;
      split2(Wg[col * DDIM + k0 + j], hi, lo);
      hi8[j] = (short)hi; lo8[j] = (short)lo;
    }
    unsigned short* base = wgfrag + (size_t)((((fh * 2 + t2) * 8 + c) * 64 + ln) * 8);
    *(short8*)base = hi8;
    *(short8*)(base + 16384) = lo8;
  } else if (id < 116736) {      // x: 65536 chunks of 8
    const int t = id - 51200;
    const float* src = x + (size_t)t * 8;
    float4 v0 = *(const float4*)src, v1 = *(const float4*)(src + 4);
    float xv[8] = {v0.x, v0.y, v0.z, v0.w, v1.x, v1.y, v1.z, v1.w};
    short8 hi8, lo8;
#pragma unroll
    for (int j = 0; j < 8; j++) {
      unsigned short hi, lo; split2(xv[j], hi, lo);
      hi8[j] = (short)hi; lo8[j] = (short)lo;
    }
    *(short8*)(xh + (size_t)t * 8) = hi8;
    *(short8*)(xl + (size_t)t * 8) = lo8;
  }
}

// ---------------------------------------------------------------------------
// Kernel 1: k = x@Wk[h], v = x@Wv[h], q = x@Wq[h]*log2e — from pre-split
// inputs.  W staged via global_load_lds (no VALU), x frags loaded as short8.
// 2x 64-row tiles/block, acc[2][8]=64 unified acc regs, (256,4): 16 waves/CU.
// Epilogue: DIRECT scatter stores.  grid (32, NHEAD, 3).
// ---------------------------------------------------------------------------
__global__ __launch_bounds__(256, 4) void proj_kernel(
    const unsigned short* __restrict__ xh, const unsigned short* __restrict__ xl,
    const unsigned short* __restrict__ wpre,
    _Float16* __restrict__ kfo, _Float16* __restrict__ vfo,
    _Float16* __restrict__ qfo)
{
  __shared__ alignas(16) unsigned short whi[8192];
  __shared__ alignas(16) unsigned short wlo[8192];
  const int tid = threadIdx.x, lane = tid & 63, wave = tid >> 6;
  const int l4 = lane & 15, quad = lane >> 4;
  const int h = blockIdx.y, z = blockIdx.z;
  const unsigned short* wb = wpre + (size_t)((z * 8 + h) * 2) * 16384;

  floatx4 acc[2][8];
#pragma unroll
  for (int t4 = 0; t4 < 2; t4++)
#pragma unroll
    for (int c = 0; c < 8; c++) acc[t4][c] = (floatx4)0.f;

  for (int fh = 0; fh < 2; fh++) {
    {
      const unsigned short* src = wb + fh * 16384;
      const unsigned short* sh = src + wave * 2048 + lane * 8;
      const unsigned short* sl = src + 8192 + wave * 2048 + lane * 8;
      unsigned short* dh = &whi[wave * 2048];
      unsigned short* dl = &wlo[wave * 2048];
#pragma unroll
      for (int it = 0; it < 4; it++) {
        async_cp16(sh + it * 512, dh + it * 512);
        async_cp16(sl + it * 512, dl + it * 512);
      }
    }
    __syncthreads();  // compiler drains vmcnt before barrier

#pragma unroll
    for (int t4 = 0; t4 < 2; t4++) {
      const int row = blockIdx.x * 128 + t4 * 64 + wave * 16 + l4;
      const size_t xo = (size_t)row * DDIM + fh * 64 + quad * 8;
      short8 ah[2], al[2];
      ah[0] = *(const short8*)(xh + xo);
      ah[1] = *(const short8*)(xh + xo + 32);
      al[0] = *(const short8*)(xl + xo);
      al[1] = *(const short8*)(xl + xo + 32);
#pragma unroll
      for (int t2 = 0; t2 < 2; t2++) {
#pragma unroll
        for (int c = 0; c < 8; c++) {
          const int col = c * 16 + l4;
          const int idx = (col * 8 + ((t2 * 4 + quad) ^ (col & 7))) * 8;
          short8 bh = *(const short8*)&whi[idx];
          short8 bl = *(const short8*)&wlo[idx];
          acc[t4][c] = __builtin_amdgcn_mfma_f32_16x16x32_bf16(ah[t2], bh, acc[t4][c], 0, 0, 0);
          acc[t4][c] = __builtin_amdgcn_mfma_f32_16x16x32_bf16(al[t2], bh, acc[t4][c], 0, 0, 0);
          acc[t4][c] = __builtin_amdgcn_mfma_f32_16x16x32_bf16(ah[t2], bl, acc[t4][c], 0, 0, 0);
        }
      }
    }
    __syncthreads();
  }

  const int rb = wave * 16 + quad * 4;
#pragma unroll
  for (int t4 = 0; t4 < 2; t4++) {
    const int tile = blockIdx.x * 2 + t4;
    const size_t tilebase = (size_t)(h * 64 + tile) * 8192;
#pragma unroll
    for (int c = 0; c < 8; c++) {
      const int d = c * 16 + l4;
#pragma unroll
      for (int r = 0; r < 4; r++) {
        const int kl = rb + r;
        const float val = acc[t4][c][r];
        if (z == 0) {
          const int c2 = kl >> 4, l4k = kl & 15;
          const int tt = d >> 5, qd = (d >> 3) & 3, jj = d & 7;
          const int qX = qd ^ ((l4k >> 1) & 3);
          kfo[tilebase + (size_t)((c2 * 4 + tt) * 16 + l4k) * 32 + qX * 8 + jj] =
              (_Float16)val;
        } else if (z == 1) {
          const int c2 = d >> 4, l4v = d & 15;
          const int tt = kl >> 5, qd = (kl >> 3) & 3, jj = kl & 7;
          const int qX = qd ^ ((l4v >> 1) & 3);
          vfo[tilebase + (size_t)((c2 * 2 + tt) * 16 + l4v) * 32 + qX * 8 + jj] =
              (_Float16)val;
        } else {
          // q: row-major fp16, scaled by log2(e) for base-2 softmax
          qfo[((size_t)h * NROWS + (size_t)tile * 64 + kl) * DDIM + d] =
              (_Float16)(val * LOG2E);
        }
      }
    }
  }
}

// ---------------------------------------------------------------------------
// Kernel 2: flash attention. 64 q-rows/block, SPLIT-K x2.  Round-6 skeleton
// + round-8 P row-swizzle (conflicts 1.05M) + ROUND 11: t=0 V-fragment loads
// hoisted to right after softmax's exp2 — P-store + rescale + ap read (~400
// cyc) cover their L2 latency instead of the first PV MFMA eating it.  t=1
// V loads stay late (issued during PV t=0).  Register peak at P-store:
// acc 36 + aq 16 + Sf 16 + vf0 32 + misc ~20 ~= 120 <= 128 cap.
// grid 1024 = 4 blocks/CU full residency.
// ---------------------------------------------------------------------------
struct FlashLds {
  _Float16 k[2][8192];  // 32768 B
  _Float16 p[4][1024];  // 8192 B, wave-private P tile [row16-swz][8]
};

__global__ __launch_bounds__(256, 4) void flash_kernel(
    const _Float16* __restrict__ qfo, const _Float16* __restrict__ kfo,
    const _Float16* __restrict__ vfo,
    _Float16* __restrict__ op, float* __restrict__ mb, float* __restrict__ lb)
{
  __shared__ alignas(16) FlashLds lds;
  const int tid = threadIdx.x, lane = tid & 63, wave = tid >> 6;
  const int l4 = lane & 15, quad = lane >> 4;
  const int h = blockIdx.x & 7, qt = (blockIdx.x >> 3) & 63, s = blockIdx.x >> 9;
  const int q0 = qt * 64;

  // Q A-frags: row-major fp16 IS the 16x16x32 A layout (row=l4, k=quad*8+j)
  half8 aq[4];
  {
    const _Float16* qr =
        qfo + ((size_t)h * NROWS + q0 + wave * 16 + l4) * DDIM + quad * 8;
#pragma unroll
    for (int t = 0; t < 4; t++) aq[t] = *(const half8*)(qr + t * 32);
  }

  float m_run[4];
#pragma unroll
  for (int r = 0; r < 4; r++) m_run[r] = -1e30f;
  floatx4 Oacc[8], lacc = (floatx4)0.f;
#pragma unroll
  for (int c = 0; c < 8; c++) Oacc[c] = (floatx4)0.f;

  half8 vones;
#pragma unroll
  for (int j = 0; j < 8; j++) vones[j] = (_Float16)1.f;

  const _Float16* kfo_h = kfo + (size_t)h * 64 * 8192;
  const _Float16* vfo_h = vfo + (size_t)h * 64 * 8192;
  const int lq = (l4 * 4 + (quad ^ ((l4 >> 1) & 3))) * 8;
  const int kt0 = s * 32, kt1 = kt0 + 32;

  // preload K(kt0) into buffer 0 (kt0 is even for both s)
  {
    const _Float16* ks = kfo_h + (size_t)kt0 * 8192 + wave * 2048 + lane * 8;
    _Float16* kd = &lds.k[0][wave * 2048];
#pragma unroll
    for (int it = 0; it < 4; it++) async_cp16(ks + it * 512, kd + it * 512);
  }

  for (int kt = kt0; kt < kt1; ++kt) {
    const int cur = kt & 1;
    __syncthreads();  // drains K(kt) copies; all waves done with k[cur^1]

    // ---- prefetch K(kt+1) into the other buffer ----
    if (kt + 1 < kt1) {
      const _Float16* ks = kfo_h + (size_t)(kt + 1) * 8192 + wave * 2048 + lane * 8;
      _Float16* kd = &lds.k[cur ^ 1][wave * 2048];
#pragma unroll
      for (int it = 0; it < 4; it++) async_cp16(ks + it * 512, kd + it * 512);
    }

    // ---- S = Q @ K^T (K from LDS buffer cur); S is in base-2 units ----
    floatx4 Sf[4];
#pragma unroll
    for (int c = 0; c < 4; c++) Sf[c] = (floatx4)0.f;
    __builtin_amdgcn_s_setprio(1);
#pragma unroll
    for (int t = 0; t < 4; t++) {
      half8 b[4];
#pragma unroll
      for (int c = 0; c < 4; c++)
        b[c] = *(const half8*)&lds.k[cur][(c * 4 + t) * 512 + lq];
#pragma unroll
      for (int c = 0; c < 4; c++)
        Sf[c] = __builtin_amdgcn_mfma_f32_16x16x32_f16(aq[t], b[c], Sf[c], 0, 0, 0);
    }
    __builtin_amdgcn_s_setprio(0);

    // ---- softmax (base-2): DPP row-max (VALU-only), exp2 ----
    float alpha[4];
    {
      float mt[4];
#pragma unroll
      for (int r = 0; r < 4; r++)
        mt[r] = fmaxf(fmaxf(Sf[0][r], Sf[1][r]), fmaxf(Sf[2][r], Sf[3][r]));
#pragma unroll
      for (int r = 0; r < 4; r++) mt[r] = dpp_max16(mt[r]);
#pragma unroll
      for (int r = 0; r < 4; r++) {
        const float mn = fmaxf(m_run[r], mt[r]);
        alpha[r] = __ocml_native_exp2_f32(m_run[r] - mn);
        m_run[r] = mn;
      }
#pragma unroll
      for (int r = 0; r < 4; r++)
#pragma unroll
        for (int c = 0; c < 4; c++)
          Sf[c][r] = __ocml_native_exp2_f32(Sf[c][r] - m_run[r]);
    }

    // ---- t=0 V frags: issue NOW — P-store + rescale cover their latency ----
    half8 vf0[8];
    {
      const _Float16* vtb = vfo_h + (size_t)kt * 8192 + lq;
#pragma unroll
      for (int c = 0; c < 8; c++)
        vf0[c] = *(const half8*)(vtb + c * 1024);
    }

    // ---- P: C-layout -> A-layout, wave-private LDS, row-swizzled ----
#pragma unroll
    for (int c = 0; c < 4; c++)
#pragma unroll
      for (int r = 0; r < 4; r++) {
        const int row_s = (c * 2 + (l4 >> 3)) * 16 + quad * 4 + r;
        const int rs = row_s ^ ((row_s >> 2) & 7);
        lds.p[wave][rs * 8 + (l4 & 7)] = (_Float16)Sf[c][r];
      }

    // ---- rescale O/l (alpha dies here) ----
    {
      const bool moved = (alpha[0] != 1.f) | (alpha[1] != 1.f) |
                         (alpha[2] != 1.f) | (alpha[3] != 1.f);
      if (__any(moved)) {
#pragma unroll
        for (int c = 0; c < 8; c++) {
          Oacc[c][0] *= alpha[0]; Oacc[c][1] *= alpha[1];
          Oacc[c][2] *= alpha[2]; Oacc[c][3] *= alpha[3];
        }
        lacc[0] *= alpha[0]; lacc[1] *= alpha[1];
        lacc[2] *= alpha[2]; lacc[3] *= alpha[3];
      }
    }

    // ---- PV t=0 (vf0 ready); t=1 V loads issued under t=0's MFMAs ----
    {
      const int row_r0 = quad * 16 + l4;
      const int rr0 = row_r0 ^ ((row_r0 >> 2) & 7);
      half8 ap0 = *(const half8*)&lds.p[wave][rr0 * 8];

      half8 vf1[8];
      {
        const _Float16* vtb = vfo_h + (size_t)kt * 8192 + 512 + lq;
#pragma unroll
        for (int c = 0; c < 8; c++)
          vf1[c] = *(const half8*)(vtb + c * 1024);
      }

      __builtin_amdgcn_s_setprio(1);
      lacc = __builtin_amdgcn_mfma_f32_16x16x32_f16(ap0, vones, lacc, 0, 0, 0);
#pragma unroll
      for (int c = 0; c < 8; c++)
        Oacc[c] = __builtin_amdgcn_mfma_f32_16x16x32_f16(ap0, vf0[c], Oacc[c], 0, 0, 0);

      const int row_r1 = (4 + quad) * 16 + l4;
      const int rr1 = row_r1 ^ ((row_r1 >> 2) & 7);
      half8 ap1 = *(const half8*)&lds.p[wave][rr1 * 8];
      lacc = __builtin_amdgcn_mfma_f32_16x16x32_f16(ap1, vones, lacc, 0, 0, 0);
#pragma unroll
      for (int c = 0; c < 8; c++)
        Oacc[c] = __builtin_amdgcn_mfma_f32_16x16x32_f16(ap1, vf1[c], Oacc[c], 0, 0, 0);
      __builtin_amdgcn_s_setprio(0);
    }
    // no trailing barrier: next iteration's barrier covers both hazards
  }

  // ---- epilogue: unnormalized partial O (fp16) + per-row (m, l) ----
  const int rbase = wave * 16 + quad * 4;
  const size_t rowbase = (size_t)(s * NHEAD + h) * NROWS + q0 + rbase;
#pragma unroll
  for (int c = 0; c < 8; c++) {
    const int col = c * 16 + l4;
#pragma unroll
    for (int r = 0; r < 4; r++)
      op[(rowbase + r) * DDIM + col] = (_Float16)Oacc[c][r];
  }
  if (l4 == 0) {
#pragma unroll
    for (int r = 0; r < 4; r++) {
      mb[rowbase + r] = m_run[r];
      lb[rowbase + r] = lacc[r];
    }
  }
}

// ---------------------------------------------------------------------------
// Kernel 3: FUSED merge+mlp: grid 256 x block 64 (1 wave, 16 rows) — every
// CU gets a block.  Wg read as B-frags directly from global (L2-resident);
// no LDS, no barriers.  y = x + relu((x + sum_i scr[i]*op_i) @ Wg^T + bg)
// ---------------------------------------------------------------------------
__global__ __launch_bounds__(64) void mlp_kernel(
    const float* __restrict__ x, const _Float16* __restrict__ op,
    const float* __restrict__ mb, const float* __restrict__ lb,
    const float* __restrict__ Wm,
    const unsigned short* __restrict__ wgfrag, const float* __restrict__ bg,
    float* __restrict__ out)
{
  const int lane = threadIdx.x, l4 = lane & 15, quad = lane >> 4;
  const int r0 = blockIdx.x * 16;
  const size_t nrow = (size_t)(r0 + l4);

  // merge scales for THIS lane's row (base-2 m values -> exp2)
  float scr[16];
#pragma unroll
  for (int hh = 0; hh < 8; hh++) {
    const float m1 = mb[(size_t)hh * NROWS + nrow];
    const float m2 = mb[(size_t)(NHEAD + hh) * NROWS + nrow];
    const float l1 = lb[(size_t)hh * NROWS + nrow];
    const float l2 = lb[(size_t)(NHEAD + hh) * NROWS + nrow];
    const float m  = fmaxf(m1, m2);
    const float a1 = __ocml_native_exp2_f32(m1 - m);
    const float a2 = __ocml_native_exp2_f32(m2 - m);
    const float invL = Wm[hh] / (l1 * a1 + l2 * a2);
    scr[hh] = a1 * invL;
    scr[8 + hh] = a2 * invL;
  }

  floatx4 acc[8];
#pragma unroll
  for (int c = 0; c < 8; c++) acc[c] = (floatx4)0.f;

  for (int fh = 0; fh < 2; fh++) {
    short8 ah[2], al[2];
#pragma unroll
    for (int t2 = 0; t2 < 2; t2++) {
      const int dbase = fh * 64 + t2 * 32 + quad * 8;
      const size_t xoff = nrow * DDIM + dbase;
      float4 x0 = *(const float4*)(x + xoff);
      float4 x1 = *(const float4*)(x + xoff + 4);
      float hv[8] = {x0.x, x0.y, x0.z, x0.w, x1.x, x1.y, x1.z, x1.w};
      // accumulate the 16 merge variants: hv += scr[i] * op[i][row][d0..7]
#pragma unroll
      for (int i = 0; i < 16; i++) {
        const half8 ov = *(const half8*)(op + ((size_t)i * NROWS + nrow) * DDIM + dbase);
        const float sci = scr[i];
#pragma unroll
        for (int j = 0; j < 8; j++) hv[j] += sci * (float)ov[j];
      }
#pragma unroll
      for (int j = 0; j < 8; j++) {
        unsigned short hi, lo; split2(hv[j], hi, lo);
        ah[t2][j] = (short)hi; al[t2][j] = (short)lo;
      }
    }
#pragma unroll
    for (int t2 = 0; t2 < 2; t2++) {
#pragma unroll
      for (int c = 0; c < 8; c++) {
        const unsigned short* fb =
            wgfrag + (size_t)((((fh * 2 + t2) * 8 + c) * 64 + lane) * 8);
        short8 bh = *(const short8*)fb;
        short8 bl = *(const short8*)(fb + 16384);
        acc[c] = __builtin_amdgcn_mfma_f32_16x16x32_bf16(ah[t2], bh, acc[c], 0, 0, 0);
        acc[c] = __builtin_amdgcn_mfma_f32_16x16x32_bf16(al[t2], bh, acc[c], 0, 0, 0);
        acc[c] = __builtin_amdgcn_mfma_f32_16x16x32_bf16(ah[t2], bl, acc[c], 0, 0, 0);
      }
    }
  }

  const int rbase = quad * 4;
#pragma unroll
  for (int c = 0; c < 8; c++) {
    const int col = c * 16 + l4;
    const float bgf = bg[col];
#pragma unroll
    for (int r = 0; r < 4; r++) {
      const size_t idx = (size_t)(r0 + rbase + r) * DDIM + col;
      out[idx] = x[idx] + fmaxf(acc[c][r] + bgf, 0.f);
    }
  }
}

extern "C" void kernel_launch(void* const* d_in, const int* in_sizes, int n_in,
                              void* d_out, int out_size, void* d_ws, size_t ws_size,
                              hipStream_t stream) {
  float* out = (float*)d_out;
  const int fill_blocks = (out_size + 255) / 256;

  const bool ok_sizes =
      n_in == 7 &&
      in_sizes[0] == NROWS * DDIM &&
      in_sizes[1] == NHEAD * DDIM * DDIM &&
      in_sizes[2] == NHEAD * DDIM * DDIM &&
      in_sizes[3] == NHEAD * DDIM * DDIM &&
      in_sizes[4] == NHEAD &&
      in_sizes[5] == DDIM * DDIM &&
      in_sizes[6] == DDIM &&
      out_size == NROWS * DDIM;
  if (!ok_sizes) {
    fill_kernel<<<fill_blocks, 256, 0, stream>>>(out, 1000.f, out_size);
    return;
  }

  // ws: k/v/qfo 25.2 + op(2) 16.8 + mb/lb 0.5 + wpre 1.5 + wgfrag 0.06
  //     + xh/xl 2.1  = ~46 MB
  const size_t HND = (size_t)NHEAD * NROWS * DDIM;
  const size_t ND  = (size_t)NROWS * DDIM;
  const size_t WPRE_N  = (size_t)3 * 8 * 2 * 16384;  // ushorts
  const size_t WGPRE_N = (size_t)2 * 16384;          // ushorts (hi+lo frags)
  const size_t need = 3 * HND * 2 + 2 * HND * 2 +
                      2 * (2 * (size_t)NHEAD * NROWS) * 4 +
                      (WPRE_N + WGPRE_N + 2 * ND) * 2;
  if (ws_size < need) {
    fill_kernel<<<fill_blocks, 256, 0, stream>>>(out, 500.f, out_size);
    return;
  }

  const float* x  = (const float*)d_in[0];
  const float* Wk = (const float*)d_in[1];
  const float* Wq = (const float*)d_in[2];
  const float* Wv = (const float*)d_in[3];
  const float* Wm = (const float*)d_in[4];
  const float* Wg = (const float*)d_in[5];
  const float* bg = (const float*)d_in[6];

  _Float16*       kfo    = (_Float16*)d_ws;
  _Float16*       vfo    = kfo + HND;
  _Float16*       qfo    = vfo + HND;
  _Float16*       op     = qfo + HND;                 // 2*HND
  float*          mb     = (float*)(op + 2 * HND);    // 2*NHEAD*NROWS
  float*          lb     = mb + 2 * NHEAD * NROWS;
  unsigned short* wpre   = (unsigned short*)(lb + 2 * NHEAD * NROWS);
  unsigned short* wgfrag = wpre + WPRE_N;
  unsigned short* xh     = wgfrag + WGPRE_N;
  unsigned short* xl     = xh + ND;

  (void)hipGetLastError();
  prep_kernel<<<dim3(456), 256, 0, stream>>>(Wk, Wv, Wq, Wg, x, wpre, wgfrag, xh, xl);
  proj_kernel<<<dim3(32, NHEAD, 3), 256, 0, stream>>>(xh, xl, wpre, kfo, vfo, qfo);
  flash_kernel<<<dim3(1024), 256, 0, stream>>>(qfo, kfo, vfo, op, mb, lb);
  mlp_kernel<<<dim3(256), 64, 0, stream>>>(x, op, mb, lb, Wm, wgfrag, bg, out);
  if (hipGetLastError() != hipSuccess) {
    fill_kernel<<<fill_blocks, 256, 0, stream>>>(out, 2000.f, out_size);
  }
}

// Round 12
// 212.358 us; speedup vs baseline: 1.6443x; 1.6443x over previous
//
#include <hip/hip_runtime.h>

#define NROWS 4096
#define DDIM  128
#define NHEAD 8
#define LOG2E 1.44269504088896f

// native 2^x  ->  single v_exp_f32 (ocml symbol always present in device libs)
extern "C" __device__ float __ocml_native_exp2_f32(float);

typedef __attribute__((ext_vector_type(8))) short    short8;
typedef __attribute__((ext_vector_type(8))) _Float16 half8;
typedef __attribute__((ext_vector_type(4))) float    floatx4;

__device__ __forceinline__ float bf2f(unsigned short u){
  unsigned v = ((unsigned)u) << 16;
  return __builtin_bit_cast(float, v);
}
__device__ __forceinline__ unsigned short f2bf(float f){
  unsigned u = __builtin_bit_cast(unsigned, f);
  u += 0x7FFFu + ((u >> 16) & 1u);
  return (unsigned short)(u >> 16);
}
__device__ __forceinline__ void split2(float v, unsigned short& hi, unsigned short& lo){
  hi = f2bf(v);
  lo = f2bf(v - bf2f(hi));
}
// async global->LDS, 16B per lane: LDS dest = wave-uniform base + lane*16.
__device__ __forceinline__ void async_cp16(const void* g, void* l){
  __builtin_amdgcn_global_load_lds(
      (const __attribute__((address_space(1))) void*)g,
      (__attribute__((address_space(3))) void*)l, 16, 0, 0);
}
// 16-lane (DPP row) max reduce via row_ror 8/4/2/1 — pure VALU, no lgkm.
__device__ __forceinline__ float dpp_max16(float v){
  int t;
  t = __builtin_amdgcn_update_dpp(0, __builtin_bit_cast(int, v), 0x128, 0xF, 0xF, false);
  v = fmaxf(v, __builtin_bit_cast(float, t));
  t = __builtin_amdgcn_update_dpp(0, __builtin_bit_cast(int, v), 0x124, 0xF, 0xF, false);
  v = fmaxf(v, __builtin_bit_cast(float, t));
  t = __builtin_amdgcn_update_dpp(0, __builtin_bit_cast(int, v), 0x122, 0xF, 0xF, false);
  v = fmaxf(v, __builtin_bit_cast(float, t));
  t = __builtin_amdgcn_update_dpp(0, __builtin_bit_cast(int, v), 0x121, 0xF, 0xF, false);
  v = fmaxf(v, __builtin_bit_cast(float, t));
  return v;
}

// fp32 sentinels: 500=ws too small, 1000=in_sizes mismatch, 2000=launch fail.
__global__ void fill_kernel(float* __restrict__ out, float val, int n){
  int i = blockIdx.x * 256 + threadIdx.x;
  if (i < n) out[i] = val;
}

// ---------------------------------------------------------------------------
// Kernel 0: prep — one-time bf16 hi/lo splits so proj/mlp do ZERO split2 VALU.
// W_k/v/q tiles: LDS-LINEAR chunk order with XOR swizzle baked in (proj).
// Wg: exact MFMA B-FRAGMENT order (mlp reads frags directly from global).
// x split to xh/xl row-major bf16 (direct short8 A-frag loads).
// ---------------------------------------------------------------------------
__global__ __launch_bounds__(256) void prep_kernel(
    const float* __restrict__ Wk, const float* __restrict__ Wv,
    const float* __restrict__ Wq, const float* __restrict__ Wg,
    const float* __restrict__ x,
    unsigned short* __restrict__ wpre, unsigned short* __restrict__ wgfrag,
    unsigned short* __restrict__ xh, unsigned short* __restrict__ xl)
{
  const int id = blockIdx.x * 256 + threadIdx.x;
  if (id < 49152) {              // W_k/v/q: 3 z * 8 h * 2 fh * 1024 chunks
    const int z = id >> 14, rem = id & 16383;
    const int h = rem >> 11, rem2 = rem & 2047;
    const int fh = rem2 >> 10, L = rem2 & 1023;
    const int d = L >> 3, m = L & 7;
    const int kk0 = (m ^ (d & 7)) << 3;
    const float* W = (z == 0 ? Wk : (z == 1 ? Wv : Wq)) + h * DDIM * DDIM;
    short8 hi8, lo8;
#pragma unroll
    for (int j = 0; j < 8; j++) {
      unsigned short hi, lo;
      split2(W[(fh * 64 + kk0 + j) * DDIM + d], hi, lo);
      hi8[j] = (short)hi; lo8[j] = (short)lo;
    }
    unsigned short* base = wpre + (size_t)((z * 8 + h) * 2 + fh) * 16384;
    *(short8*)(base + L * 8) = hi8;
    *(short8*)(base + 8192 + L * 8) = lo8;
  } else if (id < 51200) {       // Wg: 2048 ids = (fh, t2, c, lane), frag order
    const int t = id - 49152;
    const int fh = t >> 10, rem = t & 1023;
    const int t2 = rem >> 9, rem2 = rem & 511;
    const int c = rem2 >> 6, ln = rem2 & 63;
    const int quad = ln >> 4, l4 = ln & 15;
    const int col = c * 16 + l4;
    const int k0 = fh * 64 + t2 * 32 + quad * 8;
    short8 hi8, lo8;
#pragma unroll
    for (int j = 0; j < 8; j++) {
      unsigned short hi, lo;
      split2(Wg[col * DDIM + k0 + j], hi, lo);
      hi8[j] = (short)hi; lo8[j] = (short)lo;
    }
    unsigned short* base = wgfrag + (size_t)((((fh * 2 + t2) * 8 + c) * 64 + ln) * 8);
    *(short8*)base = hi8;
    *(short8*)(base + 16384) = lo8;
  } else if (id < 116736) {      // x: 65536 chunks of 8
    const int t = id - 51200;
    const float* src = x + (size_t)t * 8;
    float4 v0 = *(const float4*)src, v1 = *(const float4*)(src + 4);
    float xv[8] = {v0.x, v0.y, v0.z, v0.w, v1.x, v1.y, v1.z, v1.w};
    short8 hi8, lo8;
#pragma unroll
    for (int j = 0; j < 8; j++) {
      unsigned short hi, lo; split2(xv[j], hi, lo);
      hi8[j] = (short)hi; lo8[j] = (short)lo;
    }
    *(short8*)(xh + (size_t)t * 8) = hi8;
    *(short8*)(xl + (size_t)t * 8) = lo8;
  }
}

// ---------------------------------------------------------------------------
// Kernel 1: k = x@Wk[h], v = x@Wv[h], q = x@Wq[h]*log2e — from pre-split
// inputs.  W staged via global_load_lds (no VALU), x frags loaded as short8.
// 2x 64-row tiles/block, acc[2][8]=64 unified acc regs, (256,4): 16 waves/CU.
// Epilogue: DIRECT scatter stores.  grid (32, NHEAD, 3).
// ---------------------------------------------------------------------------
__global__ __launch_bounds__(256, 4) void proj_kernel(
    const unsigned short* __restrict__ xh, const unsigned short* __restrict__ xl,
    const unsigned short* __restrict__ wpre,
    _Float16* __restrict__ kfo, _Float16* __restrict__ vfo,
    _Float16* __restrict__ qfo)
{
  __shared__ alignas(16) unsigned short whi[8192];
  __shared__ alignas(16) unsigned short wlo[8192];
  const int tid = threadIdx.x, lane = tid & 63, wave = tid >> 6;
  const int l4 = lane & 15, quad = lane >> 4;
  const int h = blockIdx.y, z = blockIdx.z;
  const unsigned short* wb = wpre + (size_t)((z * 8 + h) * 2) * 16384;

  floatx4 acc[2][8];
#pragma unroll
  for (int t4 = 0; t4 < 2; t4++)
#pragma unroll
    for (int c = 0; c < 8; c++) acc[t4][c] = (floatx4)0.f;

  for (int fh = 0; fh < 2; fh++) {
    {
      const unsigned short* src = wb + fh * 16384;
      const unsigned short* sh = src + wave * 2048 + lane * 8;
      const unsigned short* sl = src + 8192 + wave * 2048 + lane * 8;
      unsigned short* dh = &whi[wave * 2048];
      unsigned short* dl = &wlo[wave * 2048];
#pragma unroll
      for (int it = 0; it < 4; it++) {
        async_cp16(sh + it * 512, dh + it * 512);
        async_cp16(sl + it * 512, dl + it * 512);
      }
    }
    __syncthreads();  // compiler drains vmcnt before barrier

#pragma unroll
    for (int t4 = 0; t4 < 2; t4++) {
      const int row = blockIdx.x * 128 + t4 * 64 + wave * 16 + l4;
      const size_t xo = (size_t)row * DDIM + fh * 64 + quad * 8;
      short8 ah[2], al[2];
      ah[0] = *(const short8*)(xh + xo);
      ah[1] = *(const short8*)(xh + xo + 32);
      al[0] = *(const short8*)(xl + xo);
      al[1] = *(const short8*)(xl + xo + 32);
#pragma unroll
      for (int t2 = 0; t2 < 2; t2++) {
#pragma unroll
        for (int c = 0; c < 8; c++) {
          const int col = c * 16 + l4;
          const int idx = (col * 8 + ((t2 * 4 + quad) ^ (col & 7))) * 8;
          short8 bh = *(const short8*)&whi[idx];
          short8 bl = *(const short8*)&wlo[idx];
          acc[t4][c] = __builtin_amdgcn_mfma_f32_16x16x32_bf16(ah[t2], bh, acc[t4][c], 0, 0, 0);
          acc[t4][c] = __builtin_amdgcn_mfma_f32_16x16x32_bf16(al[t2], bh, acc[t4][c], 0, 0, 0);
          acc[t4][c] = __builtin_amdgcn_mfma_f32_16x16x32_bf16(ah[t2], bl, acc[t4][c], 0, 0, 0);
        }
      }
    }
    __syncthreads();
  }

  const int rb = wave * 16 + quad * 4;
#pragma unroll
  for (int t4 = 0; t4 < 2; t4++) {
    const int tile = blockIdx.x * 2 + t4;
    const size_t tilebase = (size_t)(h * 64 + tile) * 8192;
#pragma unroll
    for (int c = 0; c < 8; c++) {
      const int d = c * 16 + l4;
#pragma unroll
      for (int r = 0; r < 4; r++) {
        const int kl = rb + r;
        const float val = acc[t4][c][r];
        if (z == 0) {
          const int c2 = kl >> 4, l4k = kl & 15;
          const int tt = d >> 5, qd = (d >> 3) & 3, jj = d & 7;
          const int qX = qd ^ ((l4k >> 1) & 3);
          kfo[tilebase + (size_t)((c2 * 4 + tt) * 16 + l4k) * 32 + qX * 8 + jj] =
              (_Float16)val;
        } else if (z == 1) {
          const int c2 = d >> 4, l4v = d & 15;
          const int tt = kl >> 5, qd = (kl >> 3) & 3, jj = kl & 7;
          const int qX = qd ^ ((l4v >> 1) & 3);
          vfo[tilebase + (size_t)((c2 * 2 + tt) * 16 + l4v) * 32 + qX * 8 + jj] =
              (_Float16)val;
        } else {
          // q: row-major fp16, scaled by log2(e) for base-2 softmax
          qfo[((size_t)h * NROWS + (size_t)tile * 64 + kl) * DDIM + d] =
              (_Float16)(val * LOG2E);
        }
      }
    }
  }
}

// ---------------------------------------------------------------------------
// Kernel 2: flash attention. 64 q-rows/block, SPLIT-K x2.  FINAL = round-10
// proven config (round-6 skeleton + round-8 P row-swizzle): 119-120 us,
// VGPR=64, no spill, bank conflicts 1.05M, 4 blocks/CU full residency.
// Round-11 lesson: V-load half-hoist spills (FETCH 12->87MB) — the late
// V-load placement is LOAD-BEARING for the 128-reg allocation.  Flash is
// simultaneously LDS-capped AND VGPR-capped; structural floor reached.
// ---------------------------------------------------------------------------
struct FlashLds {
  _Float16 k[2][8192];  // 32768 B
  _Float16 p[4][1024];  // 8192 B, wave-private P tile [row16-swz][8]
};

__global__ __launch_bounds__(256, 4) void flash_kernel(
    const _Float16* __restrict__ qfo, const _Float16* __restrict__ kfo,
    const _Float16* __restrict__ vfo,
    _Float16* __restrict__ op, float* __restrict__ mb, float* __restrict__ lb)
{
  __shared__ alignas(16) FlashLds lds;
  const int tid = threadIdx.x, lane = tid & 63, wave = tid >> 6;
  const int l4 = lane & 15, quad = lane >> 4;
  const int h = blockIdx.x & 7, qt = (blockIdx.x >> 3) & 63, s = blockIdx.x >> 9;
  const int q0 = qt * 64;

  // Q A-frags: row-major fp16 IS the 16x16x32 A layout (row=l4, k=quad*8+j)
  half8 aq[4];
  {
    const _Float16* qr =
        qfo + ((size_t)h * NROWS + q0 + wave * 16 + l4) * DDIM + quad * 8;
#pragma unroll
    for (int t = 0; t < 4; t++) aq[t] = *(const half8*)(qr + t * 32);
  }

  float m_run[4];
#pragma unroll
  for (int r = 0; r < 4; r++) m_run[r] = -1e30f;
  floatx4 Oacc[8], lacc = (floatx4)0.f;
#pragma unroll
  for (int c = 0; c < 8; c++) Oacc[c] = (floatx4)0.f;

  half8 vones;
#pragma unroll
  for (int j = 0; j < 8; j++) vones[j] = (_Float16)1.f;

  const _Float16* kfo_h = kfo + (size_t)h * 64 * 8192;
  const _Float16* vfo_h = vfo + (size_t)h * 64 * 8192;
  const int lq = (l4 * 4 + (quad ^ ((l4 >> 1) & 3))) * 8;
  const int kt0 = s * 32, kt1 = kt0 + 32;

  // preload K(kt0) into buffer 0 (kt0 is even for both s)
  {
    const _Float16* ks = kfo_h + (size_t)kt0 * 8192 + wave * 2048 + lane * 8;
    _Float16* kd = &lds.k[0][wave * 2048];
#pragma unroll
    for (int it = 0; it < 4; it++) async_cp16(ks + it * 512, kd + it * 512);
  }

  for (int kt = kt0; kt < kt1; ++kt) {
    const int cur = kt & 1;
    __syncthreads();  // drains K(kt) copies; all waves done with k[cur^1]

    // ---- prefetch K(kt+1) into the other buffer ----
    if (kt + 1 < kt1) {
      const _Float16* ks = kfo_h + (size_t)(kt + 1) * 8192 + wave * 2048 + lane * 8;
      _Float16* kd = &lds.k[cur ^ 1][wave * 2048];
#pragma unroll
      for (int it = 0; it < 4; it++) async_cp16(ks + it * 512, kd + it * 512);
    }

    // ---- S = Q @ K^T (K from LDS buffer cur); S is in base-2 units ----
    floatx4 Sf[4];
#pragma unroll
    for (int c = 0; c < 4; c++) Sf[c] = (floatx4)0.f;
    __builtin_amdgcn_s_setprio(1);
#pragma unroll
    for (int t = 0; t < 4; t++) {
      half8 b[4];
#pragma unroll
      for (int c = 0; c < 4; c++)
        b[c] = *(const half8*)&lds.k[cur][(c * 4 + t) * 512 + lq];
#pragma unroll
      for (int c = 0; c < 4; c++)
        Sf[c] = __builtin_amdgcn_mfma_f32_16x16x32_f16(aq[t], b[c], Sf[c], 0, 0, 0);
    }
    __builtin_amdgcn_s_setprio(0);

    // ---- softmax (base-2): DPP row-max (VALU-only), exp2 ----
    float alpha[4];
    {
      float mt[4];
#pragma unroll
      for (int r = 0; r < 4; r++)
        mt[r] = fmaxf(fmaxf(Sf[0][r], Sf[1][r]), fmaxf(Sf[2][r], Sf[3][r]));
#pragma unroll
      for (int r = 0; r < 4; r++) mt[r] = dpp_max16(mt[r]);
#pragma unroll
      for (int r = 0; r < 4; r++) {
        const float mn = fmaxf(m_run[r], mt[r]);
        alpha[r] = __ocml_native_exp2_f32(m_run[r] - mn);
        m_run[r] = mn;
      }
#pragma unroll
      for (int r = 0; r < 4; r++)
#pragma unroll
        for (int c = 0; c < 4; c++)
          Sf[c][r] = __ocml_native_exp2_f32(Sf[c][r] - m_run[r]);
    }

    // ---- P: C-layout -> A-layout, wave-private LDS, row-swizzled ----
#pragma unroll
    for (int c = 0; c < 4; c++)
#pragma unroll
      for (int r = 0; r < 4; r++) {
        const int row_s = (c * 2 + (l4 >> 3)) * 16 + quad * 4 + r;
        const int rs = row_s ^ ((row_s >> 2) & 7);
        lds.p[wave][rs * 8 + (l4 & 7)] = (_Float16)Sf[c][r];
      }

    // ---- rescale O/l BEFORE V-loads (alpha dies before vfrag lives) ----
    {
      const bool moved = (alpha[0] != 1.f) | (alpha[1] != 1.f) |
                         (alpha[2] != 1.f) | (alpha[3] != 1.f);
      if (__any(moved)) {
#pragma unroll
        for (int c = 0; c < 8; c++) {
          Oacc[c][0] *= alpha[0]; Oacc[c][1] *= alpha[1];
          Oacc[c][2] *= alpha[2]; Oacc[c][3] *= alpha[3];
        }
        lacc[0] *= alpha[0]; lacc[1] *= alpha[1];
        lacc[2] *= alpha[2]; lacc[3] *= alpha[3];
      }
    }

    // ---- O += P@V, l += P@ones;  t-SPLIT: 8 V-frags (32 regs) at a time ----
#pragma unroll
    for (int t = 0; t < 2; t++) {
      half8 vf[8];
      {
        const _Float16* vtb = vfo_h + (size_t)kt * 8192 + t * 512 + lq;
#pragma unroll
        for (int c = 0; c < 8; c++)
          vf[c] = *(const half8*)(vtb + c * 1024);
      }
      const int row_r = (t * 4 + quad) * 16 + l4;
      const int rr = row_r ^ ((row_r >> 2) & 7);
      half8 ap = *(const half8*)&lds.p[wave][rr * 8];
      __builtin_amdgcn_s_setprio(1);
      lacc = __builtin_amdgcn_mfma_f32_16x16x32_f16(ap, vones, lacc, 0, 0, 0);
#pragma unroll
      for (int c = 0; c < 8; c++)
        Oacc[c] = __builtin_amdgcn_mfma_f32_16x16x32_f16(ap, vf[c], Oacc[c], 0, 0, 0);
      __builtin_amdgcn_s_setprio(0);
    }
    // no trailing barrier: next iteration's barrier covers both hazards
  }

  // ---- epilogue: unnormalized partial O (fp16) + per-row (m, l) ----
  const int rbase = wave * 16 + quad * 4;
  const size_t rowbase = (size_t)(s * NHEAD + h) * NROWS + q0 + rbase;
#pragma unroll
  for (int c = 0; c < 8; c++) {
    const int col = c * 16 + l4;
#pragma unroll
    for (int r = 0; r < 4; r++)
      op[(rowbase + r) * DDIM + col] = (_Float16)Oacc[c][r];
  }
  if (l4 == 0) {
#pragma unroll
    for (int r = 0; r < 4; r++) {
      mb[rowbase + r] = m_run[r];
      lb[rowbase + r] = lacc[r];
    }
  }
}

// ---------------------------------------------------------------------------
// Kernel 3: FUSED merge+mlp: grid 256 x block 64 (1 wave, 16 rows) — every
// CU gets a block.  Wg read as B-frags directly from global (L2-resident);
// no LDS, no barriers.  y = x + relu((x + sum_i scr[i]*op_i) @ Wg^T + bg)
// ---------------------------------------------------------------------------
__global__ __launch_bounds__(64) void mlp_kernel(
    const float* __restrict__ x, const _Float16* __restrict__ op,
    const float* __restrict__ mb, const float* __restrict__ lb,
    const float* __restrict__ Wm,
    const unsigned short* __restrict__ wgfrag, const float* __restrict__ bg,
    float* __restrict__ out)
{
  const int lane = threadIdx.x, l4 = lane & 15, quad = lane >> 4;
  const int r0 = blockIdx.x * 16;
  const size_t nrow = (size_t)(r0 + l4);

  // merge scales for THIS lane's row (base-2 m values -> exp2)
  float scr[16];
#pragma unroll
  for (int hh = 0; hh < 8; hh++) {
    const float m1 = mb[(size_t)hh * NROWS + nrow];
    const float m2 = mb[(size_t)(NHEAD + hh) * NROWS + nrow];
    const float l1 = lb[(size_t)hh * NROWS + nrow];
    const float l2 = lb[(size_t)(NHEAD + hh) * NROWS + nrow];
    const float m  = fmaxf(m1, m2);
    const float a1 = __ocml_native_exp2_f32(m1 - m);
    const float a2 = __ocml_native_exp2_f32(m2 - m);
    const float invL = Wm[hh] / (l1 * a1 + l2 * a2);
    scr[hh] = a1 * invL;
    scr[8 + hh] = a2 * invL;
  }

  floatx4 acc[8];
#pragma unroll
  for (int c = 0; c < 8; c++) acc[c] = (floatx4)0.f;

  for (int fh = 0; fh < 2; fh++) {
    short8 ah[2], al[2];
#pragma unroll
    for (int t2 = 0; t2 < 2; t2++) {
      const int dbase = fh * 64 + t2 * 32 + quad * 8;
      const size_t xoff = nrow * DDIM + dbase;
      float4 x0 = *(const float4*)(x + xoff);
      float4 x1 = *(const float4*)(x + xoff + 4);
      float hv[8] = {x0.x, x0.y, x0.z, x0.w, x1.x, x1.y, x1.z, x1.w};
      // accumulate the 16 merge variants: hv += scr[i] * op[i][row][d0..7]
#pragma unroll
      for (int i = 0; i < 16; i++) {
        const half8 ov = *(const half8*)(op + ((size_t)i * NROWS + nrow) * DDIM + dbase);
        const float sci = scr[i];
#pragma unroll
        for (int j = 0; j < 8; j++) hv[j] += sci * (float)ov[j];
      }
#pragma unroll
      for (int j = 0; j < 8; j++) {
        unsigned short hi, lo; split2(hv[j], hi, lo);
        ah[t2][j] = (short)hi; al[t2][j] = (short)lo;
      }
    }
#pragma unroll
    for (int t2 = 0; t2 < 2; t2++) {
#pragma unroll
      for (int c = 0; c < 8; c++) {
        const unsigned short* fb =
            wgfrag + (size_t)((((fh * 2 + t2) * 8 + c) * 64 + lane) * 8);
        short8 bh = *(const short8*)fb;
        short8 bl = *(const short8*)(fb + 16384);
        acc[c] = __builtin_amdgcn_mfma_f32_16x16x32_bf16(ah[t2], bh, acc[c], 0, 0, 0);
        acc[c] = __builtin_amdgcn_mfma_f32_16x16x32_bf16(al[t2], bh, acc[c], 0, 0, 0);
        acc[c] = __builtin_amdgcn_mfma_f32_16x16x32_bf16(ah[t2], bl, acc[c], 0, 0, 0);
      }
    }
  }

  const int rbase = quad * 4;
#pragma unroll
  for (int c = 0; c < 8; c++) {
    const int col = c * 16 + l4;
    const float bgf = bg[col];
#pragma unroll
    for (int r = 0; r < 4; r++) {
      const size_t idx = (size_t)(r0 + rbase + r) * DDIM + col;
      out[idx] = x[idx] + fmaxf(acc[c][r] + bgf, 0.f);
    }
  }
}

extern "C" void kernel_launch(void* const* d_in, const int* in_sizes, int n_in,
                              void* d_out, int out_size, void* d_ws, size_t ws_size,
                              hipStream_t stream) {
  float* out = (float*)d_out;
  const int fill_blocks = (out_size + 255) / 256;

  const bool ok_sizes =
      n_in == 7 &&
      in_sizes[0] == NROWS * DDIM &&
      in_sizes[1] == NHEAD * DDIM * DDIM &&
      in_sizes[2] == NHEAD * DDIM * DDIM &&
      in_sizes[3] == NHEAD * DDIM * DDIM &&
      in_sizes[4] == NHEAD &&
      in_sizes[5] == DDIM * DDIM &&
      in_sizes[6] == DDIM &&
      out_size == NROWS * DDIM;
  if (!ok_sizes) {
    fill_kernel<<<fill_blocks, 256, 0, stream>>>(out, 1000.f, out_size);
    return;
  }

  // ws: k/v/qfo 25.2 + op(2) 16.8 + mb/lb 0.5 + wpre 1.5 + wgfrag 0.06
  //     + xh/xl 2.1  = ~46 MB
  const size_t HND = (size_t)NHEAD * NROWS * DDIM;
  const size_t ND  = (size_t)NROWS * DDIM;
  const size_t WPRE_N  = (size_t)3 * 8 * 2 * 16384;  // ushorts
  const size_t WGPRE_N = (size_t)2 * 16384;          // ushorts (hi+lo frags)
  const size_t need = 3 * HND * 2 + 2 * HND * 2 +
                      2 * (2 * (size_t)NHEAD * NROWS) * 4 +
                      (WPRE_N + WGPRE_N + 2 * ND) * 2;
  if (ws_size < need) {
    fill_kernel<<<fill_blocks, 256, 0, stream>>>(out, 500.f, out_size);
    return;
  }

  const float* x  = (const float*)d_in[0];
  const float* Wk = (const float*)d_in[1];
  const float* Wq = (const float*)d_in[2];
  const float* Wv = (const float*)d_in[3];
  const float* Wm = (const float*)d_in[4];
  const float* Wg = (const float*)d_in[5];
  const float* bg = (const float*)d_in[6];

  _Float16*       kfo    = (_Float16*)d_ws;
  _Float16*       vfo    = kfo + HND;
  _Float16*       qfo    = vfo + HND;
  _Float16*       op     = qfo + HND;                 // 2*HND
  float*          mb     = (float*)(op + 2 * HND);    // 2*NHEAD*NROWS
  float*          lb     = mb + 2 * NHEAD * NROWS;
  unsigned short* wpre   = (unsigned short*)(lb + 2 * NHEAD * NROWS);
  unsigned short* wgfrag = wpre + WPRE_N;
  unsigned short* xh     = wgfrag + WGPRE_N;
  unsigned short* xl     = xh + ND;

  (void)hipGetLastError();
  prep_kernel<<<dim3(456), 256, 0, stream>>>(Wk, Wv, Wq, Wg, x, wpre, wgfrag, xh, xl);
  proj_kernel<<<dim3(32, NHEAD, 3), 256, 0, stream>>>(xh, xl, wpre, kfo, vfo, qfo);
  flash_kernel<<<dim3(1024), 256, 0, stream>>>(qfo, kfo, vfo, op, mb, lb);
  mlp_kernel<<<dim3(256), 64, 0, stream>>>(x, op, mb, lb, Wm, wgfrag, bg, out);
  if (hipGetLastError() != hipSuccess) {
    fill_kernel<<<fill_blocks, 256, 0, stream>>>(out, 2000.f, out_size);
  }
}